// Round 12
// baseline (44.706 us; speedup 1.0000x reference)
//
#include <hip/hip_runtime.h>

// vol [2,160,192,160,1] f32, trf [2,160,192,160,3] f32
constexpr int B = 2, X = 160, Y = 192, Z = 160;
constexpr int TXs = 8, TYs = 8, TZs = 16;                // output tile per block (1024 voxels)
constexpr int XT = X / TXs, YT = Y / TYs, ZT = Z / TZs;  // 20, 24, 10
constexpr int NTILES = B * XT * YT * ZT;                 // 9600, divisible by 8
constexpr int NXCD = 8;
constexpr int CHUNK = NTILES / NXCD;                     // 1200
// staged region: x,y halo +-4 (16 slots), z halo +-4 (24 planes)
// LDS layout: [uz][ux*16+uy], plane stride 257 (odd -> bank = uz+16ux+uy, ~2-way)
constexpr int RX = 16, RY = 16, RZ = 24;
constexpr int PLANE = RX * RY + 1;                       // 257 words
constexpr int LDSF = RZ * PLANE;                         // 6168 words = 24672 B -> 6 blocks/CU

typedef float f32x4 __attribute__((ext_vector_type(4)));

__global__ __launch_bounds__(256, 6) void warp_kernel(
    const float* __restrict__ vol,
    const float* __restrict__ trf,
    float* __restrict__ out)
{
    __shared__ float lds[LDSF];

    const int tid = threadIdx.x;
    const int bid = blockIdx.x;

    // XCD-chunked bijective swizzle (NTILES % 8 == 0)
    const int eff = (bid & (NXCD - 1)) * CHUNK + (bid >> 3);

    int tz = eff % ZT;
    int r  = eff / ZT;
    int ty = r % YT;
    int r2 = r / YT;
    int tx = r2 % XT;
    int b  = r2 / XT;

    const int xs = tx * TXs - 4;       // region x origin
    const int ys = ty * TYs - 4;       // region y origin
    const int zs = tz * TZs - 4;       // region z origin (multiple of 4)
    const int bX = b * X;

    // ---- stage vol region into LDS (z-transposed) ----
    // 1536 f32x4 chunks: chunk c -> row = c/6 (xi=row>>4, yi=row&15), j = c%6,
    // global z = zs+4j..zs+4j+3  ->  LDS planes 4j..4j+3, in-plane index = row.
    // LDS word for elem i: (4j+i)*PLANE + row = 1028*j + row + i*PLANE.
    {
        int row = (tid * 171) >> 10;       // tid / 6 (exact for tid < 256)
        int j   = tid - 6 * row;
#pragma unroll
        for (int k = 0; k < 6; ++k) {
            int xi = row >> 4;
            int yi = row & 15;
            int xg = min(max(xs + xi, 0), X - 1);
            int yg = min(max(ys + yi, 0), Y - 1);
            int zg = min(max(zs + 4 * j, 0), Z - 4);
            const f32x4 v = *reinterpret_cast<const f32x4*>(
                vol + ((size_t)(bX + xg) * Y + yg) * Z + zg);
            int w0 = 1028 * j + row;
            lds[w0]             = v.x;
            lds[w0 + PLANE]     = v.y;
            lds[w0 + 2 * PLANE] = v.z;
            lds[w0 + 3 * PLANE] = v.w;
            int jn = j + 4;
            bool wrap = (jn >= 6);
            j   = wrap ? jn - 6 : jn;
            row += wrap ? 43 : 42;
        }
    }
    __syncthreads();

    // ---- this thread's 4 voxels: (x, y, z0v..z0v+3) ----
    int zq = tid & 3;
    int ly = (tid >> 2) & 7;
    int lx = tid >> 5;
    int x  = tx * TXs + lx;
    int y  = ty * TYs + ly;
    int z0v = tz * TZs + 4 * zq;

    size_t vid0 = ((size_t)(bX + x) * Y + y) * Z + z0v;

    const f32x4* tp = reinterpret_cast<const f32x4*>(trf + vid0 * 3);
    f32x4 t0 = tp[0], t1 = tp[1], t2 = tp[2];
    float d[12] = {t0.x, t0.y, t0.z, t0.w,
                   t1.x, t1.y, t1.z, t1.w,
                   t2.x, t2.y, t2.z, t2.w};

    const float mx = (float)(X - 1), my = (float)(Y - 1), mz = (float)(Z - 1);
    const float fxc = (float)x, fyc = (float)y;

    float res[4];
#pragma unroll
    for (int e = 0; e < 4; ++e) {
        float lxf = fxc + d[3 * e + 0];
        float lyf = fyc + d[3 * e + 1];
        float lzf = (float)(z0v + e) + d[3 * e + 2];

        // frac-based weights (exact vs reference):
        // cl = clip(l,0,max); i0 = floor(cl); corner1 weight = cl - i0.
        // At top edge cl==max -> frac==0 kills the (possibly garbage) +1 slot;
        // x/y +1 rows are value-correct clamps, z +1 plane killed by frac=0.
        float clx = fminf(fmaxf(lxf, 0.0f), mx);
        float flx = floorf(clx);
        float fx  = clx - flx;
        int   ix0 = (int)flx;

        float cly = fminf(fmaxf(lyf, 0.0f), my);
        float fly = floorf(cly);
        float fy  = cly - fly;
        int   iy0 = (int)fly;

        float clz = fminf(fmaxf(lzf, 0.0f), mz);
        float flz = floorf(clz);
        float fz  = clz - flz;
        int   iz0 = (int)flz;

        int ux0 = ix0 - xs, uy0 = iy0 - ys, uz0 = iz0 - zs;

        bool ok = ((unsigned)ux0 < (unsigned)(RX - 1)) &
                  ((unsigned)uy0 < (unsigned)(RY - 1)) &
                  ((unsigned)uz0 < (unsigned)(RZ - 1));

        float v000, v001, v010, v011, v100, v101, v110, v111;
        if (ok) {
            // one base + 8 ds_read_b32 with immediate offsets
            int w = uz0 * PLANE + (ux0 << 4) + uy0;
            v000 = lds[w];                 // (x0,y0,z0)
            v001 = lds[w + PLANE];         // (x0,y0,z1)
            v010 = lds[w + 1];             // (x0,y1,z0)
            v011 = lds[w + PLANE + 1];     // (x0,y1,z1)
            v100 = lds[w + 16];            // (x1,y0,z0)
            v101 = lds[w + PLANE + 16];    // (x1,y0,z1)
            v110 = lds[w + 17];            // (x1,y1,z0)
            v111 = lds[w + PLANE + 17];    // (x1,y1,z1)
        } else {
            int ix1 = min(ix0 + 1, X - 1);
            int iy1 = min(iy0 + 1, Y - 1);
            int iz1 = min(iz0 + 1, Z - 1);
            size_t g00 = ((size_t)(bX + ix0) * Y + iy0) * Z;
            size_t g01 = ((size_t)(bX + ix0) * Y + iy1) * Z;
            size_t g10 = ((size_t)(bX + ix1) * Y + iy0) * Z;
            size_t g11 = ((size_t)(bX + ix1) * Y + iy1) * Z;
            v000 = vol[g00 + iz0];
            v001 = vol[g00 + iz1];
            v010 = vol[g01 + iz0];
            v011 = vol[g01 + iz1];
            v100 = vol[g10 + iz0];
            v101 = vol[g10 + iz1];
            v110 = vol[g11 + iz0];
            v111 = vol[g11 + iz1];
        }

        // trilinear lerp; exact under coincidence (c1==c0) and frac==0 kills
        float c00 = v000 + fz * (v001 - v000);
        float c01 = v010 + fz * (v011 - v010);
        float c10 = v100 + fz * (v101 - v100);
        float c11 = v110 + fz * (v111 - v110);
        float c0  = c00 + fy * (c01 - c00);
        float c1  = c10 + fy * (c11 - c10);
        res[e] = c0 + fx * (c1 - c0);
    }

    f32x4 o;
    o.x = res[0]; o.y = res[1]; o.z = res[2]; o.w = res[3];
    *reinterpret_cast<f32x4*>(out + vid0) = o;
}

extern "C" void kernel_launch(void* const* d_in, const int* in_sizes, int n_in,
                              void* d_out, int out_size, void* d_ws, size_t ws_size,
                              hipStream_t stream) {
    const float* vol = (const float*)d_in[0];
    const float* trf = (const float*)d_in[1];
    float* out = (float*)d_out;

    warp_kernel<<<NTILES, 256, 0, stream>>>(vol, trf, out);
}

// Round 14
// 41.701 us; speedup vs baseline: 1.0721x; 1.0721x over previous
//
#include <hip/hip_runtime.h>

// vol [2,160,192,160,1] f32, trf [2,160,192,160,3] f32
constexpr int B = 2, X = 160, Y = 192, Z = 160;
constexpr int TXs = 8, TYs = 8, TZs = 16;                // output tile per block (1024 voxels)
constexpr int XT = X / TXs, YT = Y / TYs, ZT = Z / TZs;  // 20, 24, 10
constexpr int NTILES = B * XT * YT * ZT;                 // 9600, divisible by 8
constexpr int NXCD = 8;
constexpr int CHUNK = NTILES / NXCD;                     // 1200
// staged region: x halo -4/+2 (15 slots), y halo +-4 (16), z halo +-4 (24)
// layout: [row = ux*16+uy][uz], row stride 27 words.
// bank = 16*ux + 27*uy + uz (mod 32): over lane structure (lx,ly,zq) this is
// exactly 2-to-1 -> wave64 minimum (free). Pad words 24..26 never read
// (uz0 <= 22, pair reads uz0,uz0+1 <= 23).
constexpr int RX = 15, RY = 16, RZ = 24;
constexpr int RSTRIDE = 27;
constexpr int NROWS = RX * RY;                           // 240
constexpr int LDSF = NROWS * RSTRIDE;                    // 6480 words = 25920 B -> 6 blocks/CU
constexpr int NCHUNKS = NROWS * 6;                       // 1440 f32x4 staging chunks

typedef float f32x4 __attribute__((ext_vector_type(4)));
typedef float f32x2a __attribute__((ext_vector_type(2), aligned(4)));

__global__ __launch_bounds__(256, 6) void warp_kernel(
    const float* __restrict__ vol,
    const float* __restrict__ trf,
    float* __restrict__ out)
{
    __shared__ float lds[LDSF];

    const int tid = threadIdx.x;
    const int bid = blockIdx.x;

    // XCD-chunked bijective swizzle (NTILES % 8 == 0)
    const int eff = (bid & (NXCD - 1)) * CHUNK + (bid >> 3);

    int tz = eff % ZT;
    int r  = eff / ZT;
    int ty = r % YT;
    int r2 = r / YT;
    int tx = r2 % XT;
    int b  = r2 / XT;

    const int xs = tx * TXs - 4;       // region x origin (15 wide: -4..+10)
    const int ys = ty * TYs - 4;       // region y origin
    const int zs = tz * TZs - 4;       // region z origin (multiple of 4)
    const int bX = b * X;

    // ---- stage vol region into LDS ----
    // chunk c in [0,1440): row = c/6 (xi=row>>4 in 0..14, yi=row&15), j = c%6,
    // global z = zs+4j.. (clamped); LDS words row*27 + 4j .. +3.
    {
#pragma unroll
        for (int k = 0; k < 6; ++k) {
            unsigned c = (unsigned)tid + k * 256u;
            if (c < (unsigned)NCHUNKS) {
                unsigned row = c / 6u;          // exact: compiler magic-mul
                unsigned j   = c - 6u * row;
                int xi  = (int)(row >> 4);
                int yi  = (int)(row & 15u);
                int xg  = min(max(xs + xi, 0), X - 1);
                int yg  = min(max(ys + yi, 0), Y - 1);
                int zg  = min(max(zs + 4 * (int)j, 0), Z - 4);
                const f32x4 v = *reinterpret_cast<const f32x4*>(
                    vol + ((size_t)(bX + xg) * Y + yg) * Z + zg);
                int a = (int)row * RSTRIDE + 4 * (int)j;
                lds[a + 0] = v.x;
                lds[a + 1] = v.y;
                lds[a + 2] = v.z;
                lds[a + 3] = v.w;
            }
        }
    }
    __syncthreads();

    // ---- this thread's 4 voxels: (x, y, z0v..z0v+3) ----
    int zq = tid & 3;
    int ly = (tid >> 2) & 7;
    int lx = tid >> 5;
    int x  = tx * TXs + lx;
    int y  = ty * TYs + ly;
    int z0v = tz * TZs + 4 * zq;

    size_t vid0 = ((size_t)(bX + x) * Y + y) * Z + z0v;

    const f32x4* tp = reinterpret_cast<const f32x4*>(trf + vid0 * 3);
    f32x4 t0 = tp[0], t1 = tp[1], t2 = tp[2];
    float d[12] = {t0.x, t0.y, t0.z, t0.w,
                   t1.x, t1.y, t1.z, t1.w,
                   t2.x, t2.y, t2.z, t2.w};

    const float mx = (float)(X - 1), my = (float)(Y - 1), mz = (float)(Z - 1);
    const float fxc = (float)x, fyc = (float)y;

    float res[4];
#pragma unroll
    for (int e = 0; e < 4; ++e) {
        float lxf = fxc + d[3 * e + 0];
        float lyf = fyc + d[3 * e + 1];
        float lzf = (float)(z0v + e) + d[3 * e + 2];

        // frac-based weights (validated exact vs reference in R11):
        // cl = clip(l,0,max); i0 = floor(cl); corner1 weight = cl - i0.
        // frac==0 at top edges kills the (possibly stale) +1 slot; clamped
        // staging rows make x/y +1 slots value-correct elsewhere.
        float clx = fminf(fmaxf(lxf, 0.0f), mx);
        float flx = floorf(clx);
        float fx  = clx - flx;
        int   ix0 = (int)flx;

        float cly = fminf(fmaxf(lyf, 0.0f), my);
        float fly = floorf(cly);
        float fy  = cly - fly;
        int   iy0 = (int)fly;

        float clz = fminf(fmaxf(lzf, 0.0f), mz);
        float flz = floorf(clz);
        float fz  = clz - flz;
        int   iz0 = (int)flz;

        int ux0 = ix0 - xs, uy0 = iy0 - ys, uz0 = iz0 - zs;

        bool ok = ((unsigned)ux0 < (unsigned)(RX - 1)) &
                  ((unsigned)uy0 < (unsigned)(RY - 1)) &
                  ((unsigned)uz0 < (unsigned)(RZ - 1));

        float v000, v001, v010, v011, v100, v101, v110, v111;
        if (ok) {
            // one base; corners at word offsets {0, 27 (+y), 432 (+x), 459}
            int w = ((ux0 << 4) + uy0) * RSTRIDE + uz0;
            f32x2a p00 = *reinterpret_cast<const f32x2a*>(&lds[w]);
            f32x2a p01 = *reinterpret_cast<const f32x2a*>(&lds[w + RSTRIDE]);
            f32x2a p10 = *reinterpret_cast<const f32x2a*>(&lds[w + 16 * RSTRIDE]);
            f32x2a p11 = *reinterpret_cast<const f32x2a*>(&lds[w + 17 * RSTRIDE]);
            v000 = p00.x; v001 = p00.y;
            v010 = p01.x; v011 = p01.y;
            v100 = p10.x; v101 = p10.y;
            v110 = p11.x; v111 = p11.y;
        } else {
            int ix1 = min(ix0 + 1, X - 1);
            int iy1 = min(iy0 + 1, Y - 1);
            int iz1 = min(iz0 + 1, Z - 1);
            size_t g00 = ((size_t)(bX + ix0) * Y + iy0) * Z;
            size_t g01 = ((size_t)(bX + ix0) * Y + iy1) * Z;
            size_t g10 = ((size_t)(bX + ix1) * Y + iy0) * Z;
            size_t g11 = ((size_t)(bX + ix1) * Y + iy1) * Z;
            v000 = vol[g00 + iz0];
            v001 = vol[g00 + iz1];
            v010 = vol[g01 + iz0];
            v011 = vol[g01 + iz1];
            v100 = vol[g10 + iz0];
            v101 = vol[g10 + iz1];
            v110 = vol[g11 + iz0];
            v111 = vol[g11 + iz1];
        }

        // trilinear lerp (z innermost), exact under clamp coincidences
        float c00 = v000 + fz * (v001 - v000);
        float c01 = v010 + fz * (v011 - v010);
        float c10 = v100 + fz * (v101 - v100);
        float c11 = v110 + fz * (v111 - v110);
        float c0  = c00 + fy * (c01 - c00);
        float c1  = c10 + fy * (c11 - c10);
        res[e] = c0 + fx * (c1 - c0);
    }

    f32x4 o;
    o.x = res[0]; o.y = res[1]; o.z = res[2]; o.w = res[3];
    *reinterpret_cast<f32x4*>(out + vid0) = o;
}

extern "C" void kernel_launch(void* const* d_in, const int* in_sizes, int n_in,
                              void* d_out, int out_size, void* d_ws, size_t ws_size,
                              hipStream_t stream) {
    const float* vol = (const float*)d_in[0];
    const float* trf = (const float*)d_in[1];
    float* out = (float*)d_out;

    warp_kernel<<<NTILES, 256, 0, stream>>>(vol, trf, out);
}